// Round 8
// baseline (937.426 us; speedup 1.0000x reference)
//
#include <hip/hip_runtime.h>
#include <hip/hip_fp16.h>

#define N_NODES 100000
#define E_EDGES 3200000
#define NG      512
#define BN_EPS  1e-5f

#define BSH     7                 // 128 nodes per bucket
#define BNODES  128
#define NBUCK   782               // ceil(100000/128)
#define NCHUNK  256
#define CHUNK   12500             // E_EDGES / NCHUNK
#define DCAP    5120              // degsort LDS capacity

typedef _Float16 h8 __attribute__((ext_vector_type(8)));
typedef float f4 __attribute__((ext_vector_type(4)));

// ---------------- zero: bucket totals, stats, pool accumulators ----------------
__global__ __launch_bounds__(256) void k_zero(int* __restrict__ btot,
                                              float* __restrict__ stats1,
                                              float* __restrict__ stats2,
                                              float* __restrict__ sums,
                                              float* __restrict__ cnt) {
  int i = blockIdx.x * 256 + threadIdx.x;
  if (i < NBUCK) btot[i] = 0;
  if (i < 128) { stats1[i] = 0.f; stats2[i] = 0.f; }
  if (i < NG * 64) sums[i] = 0.f;
  if (i < NG) cnt[i] = 0.f;
}

// ---------------- per-chunk LDS hist -> global bucket totals ----------------
__global__ __launch_bounds__(256) void kb_hist(const int* __restrict__ ei,
                                               int* __restrict__ btot) {
  __shared__ int h[NBUCK];
  const int c = blockIdx.x, tid = threadIdx.x;
  for (int b = tid; b < NBUCK; b += 256) h[b] = 0;
  __syncthreads();
  const int* dst = ei + E_EDGES + c * CHUNK;
  for (int i = tid; i < CHUNK; i += 256) atomicAdd(&h[dst[i] >> BSH], 1);
  __syncthreads();
  for (int b = tid; b < NBUCK; b += 256)
    if (h[b]) atomicAdd(&btot[b], h[b]);
}

// ---------------- exclusive scan of bucket totals -> bbase, init cursor ----------------
__global__ __launch_bounds__(1024) void kb_scan2(const int* __restrict__ btot,
                                                 int* __restrict__ bbase,
                                                 int* __restrict__ cursor) {
  __shared__ int sm[1024];
  const int tid = threadIdx.x;
  const int cval = (tid < NBUCK) ? btot[tid] : 0;
  int val = cval;
  sm[tid] = val;
  __syncthreads();
  for (int off = 1; off < 1024; off <<= 1) {
    int t = (tid >= off) ? sm[tid - off] : 0;
    __syncthreads();
    val += t;
    sm[tid] = val;
    __syncthreads();
  }
  if (tid < NBUCK) { bbase[tid] = val - cval; cursor[tid] = val - cval; }
  if (tid == NBUCK - 1) bbase[NBUCK] = val;  // == E_EDGES
}

// ---------------- partitioned scatter: reserve per-bucket ranges, write runs ----------------
__global__ __launch_bounds__(256) void kb_scatter(const int* __restrict__ ei,
                                                  int* __restrict__ cursor,
                                                  int* __restrict__ binned) {
  __shared__ int cnt[NBUCK], lcur[NBUCK], res[NBUCK];
  const int c = blockIdx.x, tid = threadIdx.x;
  for (int b = tid; b < NBUCK; b += 256) cnt[b] = 0;
  __syncthreads();
  const int* srcp = ei + c * CHUNK;
  const int* dstp = ei + E_EDGES + c * CHUNK;
  for (int i = tid; i < CHUNK; i += 256) atomicAdd(&cnt[dstp[i] >> BSH], 1);
  __syncthreads();
  for (int b = tid; b < NBUCK; b += 256) {
    res[b] = cnt[b] ? atomicAdd(&cursor[b], cnt[b]) : 0;
    lcur[b] = 0;
  }
  __syncthreads();
  for (int i = tid; i < CHUNK; i += 256) {
    const int s = srcp[i], d = dstp[i];
    const int b = d >> BSH;
    const int slot = atomicAdd(&lcur[b], 1);
    binned[res[b] + slot] = ((d & (BNODES - 1)) << 17) | s;
  }
}

// ---------------- per-bucket LDS counting sort -> coalesced CSR + row_start + dis ------
__global__ __launch_bounds__(256) void kb_degsort(const int* __restrict__ binned,
                                                  const int* __restrict__ bbase,
                                                  int* __restrict__ csr,
                                                  int* __restrict__ row_start,
                                                  float* __restrict__ dis) {
  __shared__ int sA[DCAP];
  __shared__ int sB[DCAP];
  __shared__ int h[BNODES];
  __shared__ int pre[BNODES];
  __shared__ int cur[BNODES];
  const int b = blockIdx.x, tid = threadIdx.x;
  const int e0 = bbase[b], e1 = bbase[b + 1];
  const int sz = e1 - e0;
  if (tid < BNODES) h[tid] = 0;
  __syncthreads();
  if (sz <= DCAP) {
    for (int i = tid; i < sz; i += 256) {
      const int v = binned[e0 + i];
      sA[i] = v;
      atomicAdd(&h[v >> 17], 1);
    }
  } else {
    for (int i = e0 + tid; i < e1; i += 256) atomicAdd(&h[binned[i] >> 17], 1);
  }
  __syncthreads();
  if (tid < BNODES) pre[tid] = h[tid];
  __syncthreads();
  for (int off = 1; off < BNODES; off <<= 1) {
    int t = (tid >= off && tid < BNODES) ? pre[tid - off] : 0;
    __syncthreads();
    if (tid < BNODES) pre[tid] += t;
    __syncthreads();
  }
  if (tid < BNODES) {
    const int ex = pre[tid] - h[tid];
    const int n = b * BNODES + tid;
    if (n < N_NODES) {
      row_start[n] = e0 + ex;
      dis[n] = rsqrtf((float)(h[tid] + 1));  // +1 self loop
    }
    cur[tid] = ex;
  }
  if (b == NBUCK - 1 && tid == 0) row_start[N_NODES] = E_EDGES;
  __syncthreads();
  if (sz <= DCAP) {
    for (int i = tid; i < sz; i += 256) {
      const int v = sA[i];
      const int pos = atomicAdd(&cur[v >> 17], 1);
      sB[pos] = v & 0x1FFFF;
    }
    __syncthreads();
    for (int i = tid; i < sz; i += 256) csr[e0 + i] = sB[i];
  } else {
    for (int i = e0 + tid; i < e1; i += 256) {
      const int v = binned[i];
      const int pos = atomicAdd(&cur[v >> 17], 1);
      csr[e0 + pos] = v & 0x1FFFF;
    }
  }
}

// ---------------- MFMA GEMM: y[g][n][cg] = half(dis[n] * sum_c in'[n][c]*W[c][ch]) ----
// 64 nodes/block (4 waves x 16 nodes x 64 ch). fp16 LDS tiles, 16x16x32 MFMA.
// BN=false: in = fp32 [N][K].  BN=true: in = fp16 grouped [8][N][8] (gather output),
// BN affine applied during staging. Output y in grouped layout [8][N][8] fp16.
template <int K, bool BN>
__global__ __launch_bounds__(256) void k_gemm(const void* __restrict__ in_,
                                              const float* __restrict__ W,
                                              const float* __restrict__ dis,
                                              const float* __restrict__ stats,
                                              const float* __restrict__ gam,
                                              const float* __restrict__ bet,
                                              __half* __restrict__ y) {
  __shared__ _Float16 xs[64 * 72];   // [node][c in chunk], stride 72
  __shared__ _Float16 wt[64 * 72];   // [ch][c in chunk], stride 72
  __shared__ float scv[64], shv[64];
  const int tid = threadIdx.x;
  const int lane = tid & 63, wv = tid >> 6;
  const int quad = lane >> 4, mrow = lane & 15;
  const int n0 = blockIdx.x * 64;
  if (BN && tid < 64) {
    const float m = stats[tid] * (1.0f / N_NODES);
    const float v = stats[64 + tid] * (1.0f / N_NODES) - m * m;
    const float sc = rsqrtf(v + BN_EPS) * gam[tid];
    scv[tid] = sc;
    shv[tid] = bet[tid] - m * sc;
  }
  f4 acc[4];
#pragma unroll
  for (int t = 0; t < 4; ++t) acc[t] = (f4){0.f, 0.f, 0.f, 0.f};

  for (int c0 = 0; c0 < K; c0 += 64) {
    __syncthreads();
    {  // stage x chunk: 64 nodes x 64 c -> fp16
      const int n = tid >> 2, seg = (tid & 3) * 16;
      const int nn = min(n0 + n, N_NODES - 1);
      if (!BN) {
        const float* src = (const float*)in_ + (size_t)nn * K + c0 + seg;
#pragma unroll
        for (int i = 0; i < 4; ++i) {
          const float4 v = *(const float4*)&src[i * 4];
          __half2 a = __floats2half2_rn(v.x, v.y);
          __half2 b = __floats2half2_rn(v.z, v.w);
          *(__half2*)&xs[n * 72 + seg + i * 4] = a;
          *(__half2*)&xs[n * 72 + seg + i * 4 + 2] = b;
        }
      } else {
        // grouped fp16 input: channels seg..seg+15 = groups seg/8, seg/8+1
#pragma unroll
        for (int gg = 0; gg < 2; ++gg) {
          const int g = (seg >> 3) + gg;
          const __half* src = (const __half*)in_ + ((size_t)g * N_NODES + nn) * 8;
#pragma unroll
          for (int i = 0; i < 4; ++i) {
            const __half2 hv = *(const __half2*)&src[i * 2];
            const float2 f = __half22float2(hv);
            const int ch = g * 8 + i * 2;
            const float a = f.x * scv[ch] + shv[ch];
            const float b = f.y * scv[ch + 1] + shv[ch + 1];
            *(__half2*)&xs[n * 72 + ch] = __floats2half2_rn(a, b);
          }
        }
      }
    }
    {  // stage W chunk transposed: wt[ch][c]
      const int c = tid >> 2, seg = (tid & 3) * 16;
      const float* src = &W[(size_t)(c0 + c) * 64 + seg];
#pragma unroll
      for (int i = 0; i < 4; ++i) {
        const float4 v = *(const float4*)&src[i * 4];
        wt[(seg + i * 4 + 0) * 72 + c] = (_Float16)v.x;
        wt[(seg + i * 4 + 1) * 72 + c] = (_Float16)v.y;
        wt[(seg + i * 4 + 2) * 72 + c] = (_Float16)v.z;
        wt[(seg + i * 4 + 3) * 72 + c] = (_Float16)v.w;
      }
    }
    __syncthreads();
#pragma unroll
    for (int ks = 0; ks < 2; ++ks) {
      const int kb = ks * 32 + quad * 8;
      const h8 a = *(const h8*)&xs[(wv * 16 + mrow) * 72 + kb];
#pragma unroll
      for (int t4 = 0; t4 < 4; ++t4) {
        const h8 b = *(const h8*)&wt[(t4 * 16 + mrow) * 72 + kb];
        acc[t4] = __builtin_amdgcn_mfma_f32_16x16x32_f16(a, b, acc[t4], 0, 0, 0);
      }
    }
  }
  __syncthreads();
  // epilogue: scale by dis, write D (col=mrow=ch, row=quad*4+r=node) into ys=xs
  _Float16* ys = xs;
#pragma unroll
  for (int r = 0; r < 4; ++r) {
    const int nl = wv * 16 + quad * 4 + r;
    const int n = n0 + nl;
    const float d = (n < N_NODES) ? dis[n] : 0.f;
#pragma unroll
    for (int t4 = 0; t4 < 4; ++t4) {
      ys[nl * 72 + t4 * 16 + mrow] = (_Float16)(d * acc[t4][r]);
    }
  }
  __syncthreads();
  // store grouped: y[g][n0+n][0..7]
#pragma unroll
  for (int rep = 0; rep < 2; ++rep) {
    const int idx = tid + rep * 256;
    const int g = idx & 7, n = idx >> 3;
    const int node = n0 + n;
    if (node < N_NODES) {
      *(uint4*)&y[((size_t)g * N_NODES + node) * 8] = *(const uint4*)&ys[n * 72 + g * 8];
    }
  }
}

// ---------------- XCD channel-sliced gather ----------------
// group g = blockIdx&7 owns channels [8g, 8g+8): its y slice (1.6MB) stays L2-hot.
// lane = (edge slot es=lane>>2 in 0..15, channel dword cd=lane&3).
template <bool POOL>
__global__ __launch_bounds__(256) void k_gather(const int* __restrict__ csr,
                                                const int* __restrict__ rs,
                                                const __half* __restrict__ y,
                                                const float* __restrict__ dis,
                                                const float* __restrict__ bias,
                                                __half* __restrict__ hout,
                                                float* __restrict__ stats,
                                                const int* __restrict__ batch,
                                                float* __restrict__ sums,
                                                float* __restrict__ cnt) {
  const int tid = threadIdx.x;
  const int lane = tid & 63, wv = tid >> 6;
  const int es = lane >> 2, cd = lane & 3;
  const int g = blockIdx.x & 7;
  const int wid = (blockIdx.x >> 3) * 4 + wv;          // 0..1023 within group
  const int nwg = (gridDim.x >> 3) * 4;                // waves per group
  const int per = (N_NODES + nwg - 1) / nwg;
  const int n0 = wid * per;
  const int n1 = min(N_NODES, n0 + per);
  const __half* yg = y + (size_t)g * N_NODES * 8;
  const float bx = bias[g * 8 + 2 * cd], by = bias[g * 8 + 2 * cd + 1];
  float s1x = 0.f, s1y = 0.f, s2x = 0.f, s2y = 0.f;
  int curg = -1, run = 0;
  float px = 0.f, py = 0.f;
  for (int n = n0; n < n1; ++n) {
    const int e0 = rs[n], end = rs[n + 1];
    float ax = 0.f, ay = 0.f;
    if (es == 0) {  // self-loop term once
      const float2 f = __half22float2(*(const __half2*)&yg[(size_t)n * 8 + 2 * cd]);
      ax = f.x; ay = f.y;
    }
    for (int e = e0 + es; e < end; e += 16) {
      const int s = __builtin_nontemporal_load(&csr[e]);
      const float2 f = __half22float2(*(const __half2*)&yg[(size_t)s * 8 + 2 * cd]);
      ax += f.x; ay += f.y;
    }
    // reduce across the 16 edge slots (lane bits 2..5)
    ax += __shfl_xor(ax, 4);  ay += __shfl_xor(ay, 4);
    ax += __shfl_xor(ax, 8);  ay += __shfl_xor(ay, 8);
    ax += __shfl_xor(ax, 16); ay += __shfl_xor(ay, 16);
    ax += __shfl_xor(ax, 32); ay += __shfl_xor(ay, 32);
    const float d = dis[n];
    const float vx = fmaxf(d * ax + bx, 0.f);
    const float vy = fmaxf(d * ay + by, 0.f);
    if (es == 0) {
      if (!POOL) {
        *(__half2*)&hout[((size_t)g * N_NODES + n) * 8 + 2 * cd] = __floats2half2_rn(vx, vy);
      }
      s1x += vx; s1y += vy;
      s2x += vx * vx; s2y += vy * vy;
    }
    if (POOL) {
      const int gr = batch[n];
      if (gr != curg) {
        if (run) {
          if (es == 0) {
            atomicAdd(&sums[curg * 64 + g * 8 + 2 * cd], px);
            atomicAdd(&sums[curg * 64 + g * 8 + 2 * cd + 1], py);
          }
          if (g == 0 && lane == 0) atomicAdd(&cnt[curg], (float)run);
        }
        curg = gr; run = 0; px = 0.f; py = 0.f;
      }
      if (es == 0) { px += vx; py += vy; }
      ++run;
    }
  }
  if (POOL && run) {
    if (es == 0) {
      atomicAdd(&sums[curg * 64 + g * 8 + 2 * cd], px);
      atomicAdd(&sums[curg * 64 + g * 8 + 2 * cd + 1], py);
    }
    if (g == 0 && lane == 0) atomicAdd(&cnt[curg], (float)run);
  }
  // block-level stat reduction for this group's 8 channels
  __shared__ float sacc[16];
  if (tid < 16) sacc[tid] = 0.f;
  __syncthreads();
  if (es == 0) {
    atomicAdd(&sacc[2 * cd], s1x);
    atomicAdd(&sacc[2 * cd + 1], s1y);
    atomicAdd(&sacc[8 + 2 * cd], s2x);
    atomicAdd(&sacc[8 + 2 * cd + 1], s2y);
  }
  __syncthreads();
  if (tid < 8) atomicAdd(&stats[g * 8 + tid], sacc[tid]);
  else if (tid < 16) atomicAdd(&stats[64 + g * 8 + (tid - 8)], sacc[tid]);
}

// ---------------- fused BN2-affine + 5-layer MLP head, one block per graph ----------------
__global__ __launch_bounds__(128) void k_mlp(const float* __restrict__ sums,
                                             const float* __restrict__ cnt,
                                             const float* __restrict__ stats,
                                             const float* __restrict__ gam,
                                             const float* __restrict__ bet,
                                             const float* __restrict__ fw1, const float* __restrict__ fb1,
                                             const float* __restrict__ fw2, const float* __restrict__ fb2,
                                             const float* __restrict__ fw3, const float* __restrict__ fb3,
                                             const float* __restrict__ fw4, const float* __restrict__ fb4,
                                             const float* __restrict__ ow, const float* __restrict__ ob,
                                             float* __restrict__ out) {
  __shared__ float u0[128], u1[128];
  const int g = blockIdx.x, t = threadIdx.x;
  if (t < 64) {
    const float m = stats[t] * (1.0f / N_NODES);
    const float v = stats[64 + t] * (1.0f / N_NODES) - m * m;
    const float sc = rsqrtf(v + BN_EPS) * gam[t];
    const float sh = bet[t] - m * sc;
    u0[t] = (sums[g * 64 + t] / fmaxf(cnt[g], 1.0f)) * sc + sh;
  }
  __syncthreads();
  if (t < 128) {
    float a = fb1[t];
    for (int k = 0; k < 64; ++k) a = fmaf(u0[k], fw1[k * 128 + t], a);
    u1[t] = fmaxf(a, 0.f);
  }
  __syncthreads();
  if (t < 64) {
    float a = fb2[t];
    for (int k = 0; k < 128; ++k) a = fmaf(u1[k], fw2[k * 64 + t], a);
    u0[t] = fmaxf(a, 0.f);
  }
  __syncthreads();
  if (t < 32) {
    float a = fb3[t];
    for (int k = 0; k < 64; ++k) a = fmaf(u0[k], fw3[k * 32 + t], a);
    u1[t] = fmaxf(a, 0.f);
  }
  __syncthreads();
  if (t < 16) {
    float a = fb4[t];
    for (int k = 0; k < 32; ++k) a = fmaf(u1[k], fw4[k * 16 + t], a);
    u0[t] = fmaxf(a, 0.f);
  }
  __syncthreads();
  if (t < 2) {
    float a = ob[t];
    for (int k = 0; k < 16; ++k) a = fmaf(u0[k], ow[k * 2 + t], a);
    out[g * 2 + t] = a;
  }
}

extern "C" void kernel_launch(void* const* d_in, const int* in_sizes, int n_in,
                              void* d_out, int out_size, void* d_ws, size_t ws_size,
                              hipStream_t stream) {
  const float* x    = (const float*)d_in[0];
  const int*   ei   = (const int*)d_in[1];
  const int*   batch= (const int*)d_in[2];
  const float* w1   = (const float*)d_in[3];
  const float* b1   = (const float*)d_in[4];
  const float* w2   = (const float*)d_in[5];
  const float* b2   = (const float*)d_in[6];
  const float* g1   = (const float*)d_in[7];
  const float* be1  = (const float*)d_in[8];
  const float* g2   = (const float*)d_in[9];
  const float* be2  = (const float*)d_in[10];
  const float* fw1  = (const float*)d_in[11]; const float* fb1 = (const float*)d_in[12];
  const float* fw2  = (const float*)d_in[13]; const float* fb2 = (const float*)d_in[14];
  const float* fw3  = (const float*)d_in[15]; const float* fb3 = (const float*)d_in[16];
  const float* fw4  = (const float*)d_in[17]; const float* fb4 = (const float*)d_in[18];
  const float* ow   = (const float*)d_in[19]; const float* ob  = (const float*)d_in[20];
  float* out = (float*)d_out;

  char* ws = (char*)d_ws;
  auto alloc = [&](size_t bytes) {
    void* p = ws;
    ws += (bytes + 255) & ~(size_t)255;
    return p;
  };
  float*  dis      = (float*)alloc((size_t)N_NODES * 4);
  int*    btot     = (int*)  alloc((size_t)NBUCK * 4);
  int*    bbase    = (int*)  alloc((size_t)(NBUCK + 1) * 4);
  int*    cursor   = (int*)  alloc((size_t)NBUCK * 4);
  int*    binned   = (int*)  alloc((size_t)E_EDGES * 4);
  int*    csr      = (int*)  alloc((size_t)E_EDGES * 4);
  int*    row_start= (int*)  alloc((size_t)(N_NODES + 1) * 4);
  __half* yH       = (__half*)alloc((size_t)N_NODES * 64 * 2);
  __half* hB       = (__half*)alloc((size_t)N_NODES * 64 * 2);
  float*  stats1   = (float*)alloc(512);
  float*  stats2   = (float*)alloc(512);
  float*  sums     = (float*)alloc((size_t)NG * 64 * 4);
  float*  cnt      = (float*)alloc((size_t)NG * 4);

  const int nblkG = (N_NODES + 63) / 64;  // 1563

  // build node-sorted CSR via reservation-based bucket binning (shared by both layers)
  k_zero    <<<128, 256, 0, stream>>>(btot, stats1, stats2, sums, cnt);
  kb_hist   <<<NCHUNK, 256, 0, stream>>>(ei, btot);
  kb_scan2  <<<1, 1024, 0, stream>>>(btot, bbase, cursor);
  kb_scatter<<<NCHUNK, 256, 0, stream>>>(ei, cursor, binned);
  kb_degsort<<<NBUCK, 256, 0, stream>>>(binned, bbase, csr, row_start, dis);

  // conv1: y1 = half(dis*(x@w1)) grouped -> yH; sliced gather(store) -> hB + stats1
  k_gemm<256, false><<<nblkG, 256, 0, stream>>>(x, w1, dis, nullptr, nullptr, nullptr, yH);
  k_gather<false><<<2048, 256, 0, stream>>>(csr, row_start, yH, dis, b1, hB, stats1,
                                            nullptr, nullptr, nullptr);

  // conv2: y2 = half(dis*(BN1(hB)@w2)) grouped -> yH; sliced gather(pool) -> sums/cnt + stats2
  k_gemm<64, true><<<nblkG, 256, 0, stream>>>(hB, w2, dis, stats1, g1, be1, yH);
  k_gather<true><<<2048, 256, 0, stream>>>(csr, row_start, yH, dis, b2, nullptr, stats2,
                                           batch, sums, cnt);

  // BN2-affine on pooled means + MLP head
  k_mlp<<<NG, 128, 0, stream>>>(sums, cnt, stats2, g2, be2,
                                fw1, fb1, fw2, fb2, fw3, fb3, fw4, fb4, ow, ob, out);
}